// Round 7
// baseline (310.364 us; speedup 1.0000x reference)
//
#include <hip/hip_runtime.h>
#include <hip/hip_bf16.h>
#include <stdint.h>
#include <stddef.h>

typedef short v8s __attribute__((ext_vector_type(8)));
typedef short v4s __attribute__((ext_vector_type(4)));
typedef float v4f __attribute__((ext_vector_type(4)));
typedef float v16f __attribute__((ext_vector_type(16)));
typedef unsigned long long u64;

#define STEPSZ 0.01f
#define MFMA16(a, b, c) __builtin_amdgcn_mfma_f32_16x16x32_bf16((a), (b), (c), 0, 0, 0)
#define MFMA32(a, b, c) __builtin_amdgcn_mfma_f32_32x32x16_bf16((a), (b), (c), 0, 0, 0)

/* workspace layout (bytes) */
#define OFF_ATT 0u        /* bf16 [4096][256] 2 MB : AtT rows (n*8+j)=A[m,n,j]*rev[j] over m */
#define OFF_GRT 2097152u  /* bf16 [4096][512] 4 MB : GramT rows (n*8+g) over n' */
#define OFF_CT  6291456u  /* f32  [512][512]  1 MB : cT rows (b*8+k) over n */
#define OFF_YB  7340032u  /* bf16 [512][256] 256 KB: y blades rows (b*8+i) over m */
#define OFF_XB0 7602176u  /* bf16 [512][512] 512 KB: x operand buffer 0 */
#define OFF_XB1 8126464u  /* bf16 [512][512] 512 KB: x operand buffer 1 */
#define OFF_BAR 8650752u  /* int  [16 cl][64] flags (256B/cluster) + ctrl[16] */

__device__ __forceinline__ int csign(int i, int j) {  /* reorder parity of e_i * e_j */
  return (__popc((i >> 1) & j) + __popc((i >> 2) & j)) & 1;
}

/* ---- agent-scope (L3 coherence point) data path: slow/fallback protocol ---- */
__device__ __forceinline__ v8s aload16(const void* p) {
  u64 lo = __hip_atomic_load((const u64*)p, __ATOMIC_RELAXED, __HIP_MEMORY_SCOPE_AGENT);
  u64 hi = __hip_atomic_load((const u64*)p + 1, __ATOMIC_RELAXED, __HIP_MEMORY_SCOPE_AGENT);
  union { u64 u; v4s s; } a, b;
  a.u = lo; b.u = hi;
  return __builtin_shufflevector(a.s, b.s, 0, 1, 2, 3, 4, 5, 6, 7);
}

/* ---- XCD-local fast path: sc0 = bypass L1, hit the XCD-shared L2 ---- */
__device__ __forceinline__ int ld_flag_sc0(const int* p) {
  int v;
  asm volatile("global_load_dword %0, %1, off sc0\n\ts_waitcnt vmcnt(0)"
               : "=&v"(v) : "v"(p) : "memory");
  return v;
}

/* fused prep: blocks 0-511 build AtT, 512-1023 build yb, block 1024 zeros flags */
__global__ void prep_fused(const float* __restrict__ A, const float* __restrict__ y,
                           __hip_bfloat16* __restrict__ AtT, __hip_bfloat16* __restrict__ yb,
                           int* __restrict__ bar) {
  const int b = blockIdx.x;
  const int t = threadIdx.x;
  if (b < 512) {
    const int n = b, m = t;
    const float* ap = A + ((size_t)m * 512 + n) * 8;
    const float rev[8] = {1.f, 1.f, 1.f, -1.f, 1.f, -1.f, -1.f, -1.f};
#pragma unroll
    for (int j = 0; j < 8; ++j)
      AtT[(size_t)(n * 8 + j) * 256 + m] = __float2bfloat16(ap[j] * rev[j]);
  } else if (b < 1024) {
    const int r = b - 512, m = t;
    yb[(size_t)r * 256 + m] = __float2bfloat16(y[((size_t)(r >> 3) * 256 + m) * 8 + (r & 7)]);
  } else {
    for (int i = t; i < 1056; i += 256)
      __hip_atomic_store(bar + i, 0, __ATOMIC_RELAXED, __HIP_MEMORY_SCOPE_AGENT);
  }
}

/* fused c + gram: blocks [0,512) compute cT (64x8), [512,4608) compute GramT (64x64).
 * Shared structure: 64x64 MFMA tile, K=256, LDS blade recombine. */
__global__ __launch_bounds__(256) void cg_kernel(const __hip_bfloat16* __restrict__ yb,
                                                 const __hip_bfloat16* __restrict__ AtT,
                                                 float* __restrict__ cT,
                                                 __hip_bfloat16* __restrict__ GrT) {
  __shared__ float Pt[64 * 66];
  const int tid = threadIdx.x;
  const int wave = tid >> 6, lane = tid & 63;
  const int fr = lane & 15, fq = lane >> 4;
  const int wr = (wave >> 1) * 32, wc = (wave & 1) * 32;
  const int isC = blockIdx.x < 512;
  const int gb = isC ? blockIdx.x : blockIdx.x - 512;
  const int bx = gb & 63, by = gb >> 6;
  const int r0 = by * 64, c0 = bx * 64;
  const __hip_bfloat16* Asrc = isC ? yb : AtT;
  v4f acc[2][2] = {};
  for (int k0 = 0; k0 < 256; k0 += 32) {
    v8s a0 = *(const v8s*)(Asrc + (size_t)(r0 + wr + fr) * 256 + k0 + fq * 8);
    v8s a1 = *(const v8s*)(Asrc + (size_t)(r0 + wr + 16 + fr) * 256 + k0 + fq * 8);
    v8s b0 = *(const v8s*)(AtT + (size_t)(c0 + wc + fr) * 256 + k0 + fq * 8);
    v8s b1 = *(const v8s*)(AtT + (size_t)(c0 + wc + 16 + fr) * 256 + k0 + fq * 8);
    acc[0][0] = MFMA16(a0, b0, acc[0][0]);
    acc[0][1] = MFMA16(a0, b1, acc[0][1]);
    acc[1][0] = MFMA16(a1, b0, acc[1][0]);
    acc[1][1] = MFMA16(a1, b1, acc[1][1]);
  }
#pragma unroll
  for (int r = 0; r < 2; ++r)
#pragma unroll
    for (int c = 0; c < 2; ++c)
#pragma unroll
      for (int v = 0; v < 4; ++v)
        Pt[(wr + r * 16 + fq * 4 + v) * 66 + wc + c * 16 + fr] = acc[r][c][v];
  __syncthreads();
  if (isC) {
    for (int o = tid; o < 512; o += 256) {
      const int bl = o >> 6, k = (o >> 3) & 7, nl = o & 7;
      float s = 0.f;
#pragma unroll
      for (int j = 0; j < 8; ++j) {
        const int i = k ^ j;
        const float p = Pt[(bl * 8 + i) * 66 + nl * 8 + j];
        s += csign(i, j) ? -p : p;
      }
      cT[((size_t)((by * 8 + bl) * 8 + k)) * 512 + bx * 8 + nl] = s;
    }
  } else {
    const float rev[8] = {1.f, 1.f, 1.f, -1.f, 1.f, -1.f, -1.f, -1.f};
    for (int o = tid; o < 512; o += 256) {
      const int nl = o >> 6, g = (o >> 3) & 7, npl = o & 7;
      float s = 0.f;
#pragma unroll
      for (int j = 0; j < 8; ++j) {
        const int i = g ^ j;
        const float sg = (csign(i, j) ? -1.f : 1.f) * rev[i];
        s += sg * Pt[(npl * 8 + i) * 66 + nl * 8 + j];
      }
      GrT[((size_t)((bx * 8 + nl) * 8 + g)) * 512 + by * 8 + npl] = __float2bfloat16(s);
    }
  }
}

/* Persistent kernel: 256 blocks x 512 thr, 1 block/CU.
 * Cluster = 16 blocks sharing bid&7 (same XCD under %8 mapping; verified at
 * runtime via HW_REG_XCC_ID purity check -> L2 protocol, else L3 fallback).
 * Sync protocol = round-1 proven skeleton (block flags, poll all peers,
 * barrier-drained publish, tid0 flag post). Compute phase: dual independent
 * MFMA accumulator chains halve the 32-deep dependent-chain latency.
 * (Round-7 control run: byte-exact resubmit of the round-3 build that
 * passed at 310us total / 193us ista, to arbitrate code vs infra after
 * three consecutive harness failures on publish-store variants.) */
__global__ __launch_bounds__(512, 2) void ista_persist(
    const __hip_bfloat16* __restrict__ GrT, const float* __restrict__ cT,
    __hip_bfloat16* __restrict__ xb0, __hip_bfloat16* __restrict__ xb1,
    float* __restrict__ out, int* __restrict__ bars) {
  /* [0,32K) x-stage [32 rows][1024 B] (chunk c at slot c^(row&15)) |
   * [32K,+37376) Pt f32 [32][pitch 292] blade-swizzled */
  __shared__ __align__(16) char lds[32768 + 37376];
  float* const Pt = (float*)(lds + 32768);
  __shared__ int mode_sh;

  const int tid = threadIdx.x;
  const int wave = tid >> 6, lane = tid & 63;
  const int lr = lane & 31, lh = lane >> 5;  // tile row, k-half
  const int cl = (blockIdx.x & 7) * 2 + (blockIdx.x >> 7);
  const int w = (blockIdx.x >> 3) & 15;
  const int rowbase = cl * 32;
  int* const flags = bars + cl * 64;  /* 256B per cluster: no cross-cluster lines */
  int* const ctrl = bars + 1024;      /* [0]=arrive count, [1..8]=per-group XCD mask */

  /* persistent B in VGPRs: GramT rows [w*256 + wave*32 + lr], all K (plain
   * cached loads; GrT immutable and never invalidated - no fences anywhere) */
  v8s B[32];
  {
    const __hip_bfloat16* gB = GrT + (size_t)(w * 256 + wave * 32 + lr) * 512 + lh * 8;
#pragma unroll
    for (int kt = 0; kt < 32; ++kt) B[kt] = *(const v8s*)(gB + kt * 16);
  }

  /* one-time XCD purity probe + device barrier (overlaps the B loads above) */
  if (tid == 0) {
    unsigned xcc;
    asm volatile("s_getreg_b32 %0, hwreg(HW_REG_XCC_ID)" : "=s"(xcc));
    __hip_atomic_fetch_or((unsigned*)(ctrl + 1 + (blockIdx.x & 7)), 1u << (xcc & 31),
                          __ATOMIC_RELAXED, __HIP_MEMORY_SCOPE_AGENT);
    __hip_atomic_fetch_add(ctrl, 1, __ATOMIC_RELEASE, __HIP_MEMORY_SCOPE_AGENT);
    while (__hip_atomic_load(ctrl, __ATOMIC_RELAXED, __HIP_MEMORY_SCOPE_AGENT) < 256)
      __builtin_amdgcn_s_sleep(2);
    unsigned m = __hip_atomic_load((unsigned*)(ctrl + 1 + (blockIdx.x & 7)),
                                   __ATOMIC_RELAXED, __HIP_MEMORY_SCOPE_AGENT);
    mode_sh = (__popc(m) == 1) ? 1 : 0;
  }
  __syncthreads();
  const int fast = mode_sh;

  /* x-stage addressing */
  const int srow = tid >> 4, scol = tid & 15;
  /* epilogue mapping: 512 threads x 2 outputs (n = en*2 + {0,1}) */
  const int eb = tid >> 7, ek = (tid >> 4) & 7, en = tid & 15;
  const int xrow = rowbase + eb * 8 + ek;  // next-iter A row (b,i=k)
  const float thr = (ek == 0) ? 0.f : ((ek == 7) ? 0.002f : 0.001f);
  const float* const crow = cT + (size_t)(xrow)*512 + w * 32 + en * 2;
  const float cv0 = crow[0], cv1 = crow[1];  /* constant across iterations */
  float* const orow = out + ((size_t)(cl * 4 + eb) * 512 + w * 32 + en * 2) * 8 + ek;
  float xreg[2] = {0.f, 0.f};

  for (int it = 0; it < 50; ++it) {
    if (it > 0) {
      /* wait: all cluster members posted iter it (skip own slot) */
      if (tid < 16 && tid != w) {
        if (fast) {
          while (ld_flag_sc0(flags + tid) < it) __builtin_amdgcn_s_sleep(1);
        } else {
          while (__hip_atomic_load(flags + tid, __ATOMIC_RELAXED, __HIP_MEMORY_SCOPE_AGENT) < it)
            __builtin_amdgcn_s_sleep(1);
        }
      }
      asm volatile("" ::: "memory");
      __syncthreads();
      /* stage x_(it) into LDS: 32 rows x 1 KB */
      {
        const __hip_bfloat16* xr = (it & 1) ? xb1 : xb0;
        const __hip_bfloat16* g = xr + (size_t)(rowbase + srow) * 512 + scol * 8;
        v8s v0, v1, v2, v3;
        if (fast) {
          /* 4 pipelined sc0 loads (L1-bypass, L2-hit), one drain */
          asm volatile(
              "global_load_dwordx4 %0, %4, off sc0\n\t"
              "global_load_dwordx4 %1, %4, off offset:256 sc0\n\t"
              "global_load_dwordx4 %2, %4, off offset:512 sc0\n\t"
              "global_load_dwordx4 %3, %4, off offset:768 sc0\n\t"
              "s_waitcnt vmcnt(0)"
              : "=&v"(v0), "=&v"(v1), "=&v"(v2), "=&v"(v3)
              : "v"(g)
              : "memory");
        } else {
          v0 = aload16(g);
          v1 = aload16(g + 128);
          v2 = aload16(g + 256);
          v3 = aload16(g + 384);
        }
        const int sw = srow & 15;
        *(v8s*)(lds + srow * 1024 + (((scol + 0) ^ sw) << 4)) = v0;
        *(v8s*)(lds + srow * 1024 + (((scol + 16) ^ sw) << 4)) = v1;
        *(v8s*)(lds + srow * 1024 + (((scol + 32) ^ sw) << 4)) = v2;
        *(v8s*)(lds + srow * 1024 + (((scol + 48) ^ sw) << 4)) = v3;
      }
      __syncthreads();
      /* K-loop: 32 MFMAs in two independent chains, B from regs, A from LDS
       * (2-way swizzle = free). Dual chains halve dependent-chain latency. */
      v16f acc0 = {}, acc1 = {};
#pragma unroll
      for (int kt = 0; kt < 32; kt += 2) {
        v8s a0 = *(const v8s*)(lds + lr * 1024 + (((kt * 2 + lh) ^ (lr & 15)) << 4));
        v8s a1 = *(const v8s*)(lds + lr * 1024 + ((((kt + 1) * 2 + lh) ^ (lr & 15)) << 4));
        acc0 = MFMA32(a0, B[kt], acc0);
        acc1 = MFMA32(a1, B[kt + 1], acc1);
      }
      /* dump P tile: C/D layout col=lane&31, row=(r&3)+8*(r>>2)+4*(lane>>5).
       * col=(n,g): store g at slot g^(row&7) inside the 9-float n-slot. */
      {
        const int nsl = ((wave * 32 + lr) >> 3) * 9;
        const int gg = lr & 7;
#pragma unroll
        for (int r = 0; r < 16; ++r) {
          const int row = (r & 3) + 8 * (r >> 2) + 4 * lh;
          Pt[row * 292 + nsl + (gg ^ (row & 7))] = acc0[r] + acc1[r];
        }
      }
    }
    __syncthreads(); /* Pt visible */
    /* epilogue: blade recombine + ISTA update + x publish */
    {
      __hip_bfloat16* const xw = (it & 1) ? xb0 : xb1;
      unsigned int pack = 0;
#pragma unroll
      for (int c = 0; c < 2; ++c) {
        const int n = en * 2 + c;
        float s = 0.f;
        if (it > 0) {
          /* slot index = j ^ i = ek (constant per thread) -> 2-way banks */
          const float* pb = Pt + (size_t)(eb * 8) * 292 + n * 9 + ek;
#pragma unroll
          for (int j = 0; j < 8; ++j) {
            const int i = ek ^ j;
            const float p = pb[i * 292];
            s += csign(i, j) ? -p : p;
          }
        }
        float xv = xreg[c] - STEPSZ * (s - (c ? cv1 : cv0));
        const float ax = fabsf(xv) - thr;
        xv = (ax > 0.f) ? copysignf(ax, xv) : 0.f;
        xreg[c] = xv;
        __hip_bfloat16 h = __float2bfloat16(xv);
        unsigned short bits;
        __builtin_memcpy(&bits, &h, 2);
        pack |= ((unsigned int)bits) << (c * 16);
        if (it == 49) orow[c * 8] = xv;
      }
      unsigned int* const pdst =
          (unsigned int*)(xw + (size_t)xrow * 512 + w * 32 + en * 2);
      if (fast) {
        *(volatile unsigned int*)pdst = pack; /* write-through -> shared L2 */
      } else {
        __hip_atomic_store(pdst, pack, __ATOMIC_RELAXED, __HIP_MEMORY_SCOPE_AGENT);
      }
    }
    __syncthreads(); /* per-wave vmcnt(0) drain -> all stores at L2/L3 */
    if (tid == 0) {
      if (fast)
        *(volatile int*)(flags + w) = it + 1;
      else
        __hip_atomic_store(flags + w, it + 1, __ATOMIC_RELAXED, __HIP_MEMORY_SCOPE_AGENT);
    }
  }
}

extern "C" void kernel_launch(void* const* d_in, const int* in_sizes, int n_in,
                              void* d_out, int out_size, void* d_ws, size_t ws_size,
                              hipStream_t stream) {
  (void)in_sizes; (void)n_in; (void)out_size; (void)ws_size;
  const float* y = (const float*)d_in[0];
  const float* A = (const float*)d_in[1];
  float* out = (float*)d_out;
  char* ws = (char*)d_ws;

  __hip_bfloat16* AtT = (__hip_bfloat16*)(ws + OFF_ATT);
  __hip_bfloat16* GrT = (__hip_bfloat16*)(ws + OFF_GRT);
  float* cT = (float*)(ws + OFF_CT);
  __hip_bfloat16* yb = (__hip_bfloat16*)(ws + OFF_YB);
  __hip_bfloat16* xb0 = (__hip_bfloat16*)(ws + OFF_XB0);
  __hip_bfloat16* xb1 = (__hip_bfloat16*)(ws + OFF_XB1);
  int* bars = (int*)(ws + OFF_BAR);

  prep_fused<<<1025, 256, 0, stream>>>(A, y, AtT, yb, bars);
  cg_kernel<<<4608, 256, 0, stream>>>(yb, AtT, cT, GrT);
  ista_persist<<<256, 512, 0, stream>>>(GrT, cT, xb0, xb1, out, bars);
}

// Round 9
// 290.709 us; speedup vs baseline: 1.0676x; 1.0676x over previous
//
#include <hip/hip_runtime.h>
#include <hip/hip_bf16.h>
#include <stdint.h>
#include <stddef.h>

typedef short v8s __attribute__((ext_vector_type(8)));
typedef short v4s __attribute__((ext_vector_type(4)));
typedef float v4f __attribute__((ext_vector_type(4)));
typedef float v16f __attribute__((ext_vector_type(16)));
typedef unsigned long long u64;

#define STEPSZ 0.01f
#define MFMA16(a, b, c) __builtin_amdgcn_mfma_f32_16x16x32_bf16((a), (b), (c), 0, 0, 0)
#define MFMA32(a, b, c) __builtin_amdgcn_mfma_f32_32x32x16_bf16((a), (b), (c), 0, 0, 0)

/* workspace layout (bytes) */
#define OFF_ATT 0u        /* bf16 [4096][256] 2 MB : AtT rows (n*8+j)=A[m,n,j]*rev[j] over m */
#define OFF_GRT 2097152u  /* bf16 [4096][512] 4 MB : GramT rows (n*8+g) over n' */
#define OFF_CT  6291456u  /* f32  [512][512]  1 MB : cT rows (b*8+k) over n */
#define OFF_YB  7340032u  /* bf16 [512][256] 256 KB: y blades rows (b*8+i) over m */
#define OFF_XB0 7602176u  /* bf16 [512][512] 512 KB: x operand buffer 0 */
#define OFF_XB1 8126464u  /* bf16 [512][512] 512 KB: x operand buffer 1 */
#define OFF_BAR 8650752u  /* int  [16 cl][64] flags (256B/cluster) + ctrl[16] */

__device__ __forceinline__ int csign(int i, int j) {  /* reorder parity of e_i * e_j */
  return (__popc((i >> 1) & j) + __popc((i >> 2) & j)) & 1;
}

/* ---- agent-scope (L3 coherence point) data path: slow/fallback protocol ---- */
__device__ __forceinline__ v8s aload16(const void* p) {
  u64 lo = __hip_atomic_load((const u64*)p, __ATOMIC_RELAXED, __HIP_MEMORY_SCOPE_AGENT);
  u64 hi = __hip_atomic_load((const u64*)p + 1, __ATOMIC_RELAXED, __HIP_MEMORY_SCOPE_AGENT);
  union { u64 u; v4s s; } a, b;
  a.u = lo; b.u = hi;
  return __builtin_shufflevector(a.s, b.s, 0, 1, 2, 3, 4, 5, 6, 7);
}

/* ---- XCD-local fast path: sc0 = bypass L1, hit the XCD-shared L2 ---- */
__device__ __forceinline__ int ld_flag_sc0(const int* p) {
  int v;
  asm volatile("global_load_dword %0, %1, off sc0\n\ts_waitcnt vmcnt(0)"
               : "=&v"(v) : "v"(p) : "memory");
  return v;
}

/* fused prep: blocks 0-511 build AtT, 512-1023 build yb, block 1024 zeros flags */
__global__ void prep_fused(const float* __restrict__ A, const float* __restrict__ y,
                           __hip_bfloat16* __restrict__ AtT, __hip_bfloat16* __restrict__ yb,
                           int* __restrict__ bar) {
  const int b = blockIdx.x;
  const int t = threadIdx.x;
  if (b < 512) {
    const int n = b, m = t;
    const float* ap = A + ((size_t)m * 512 + n) * 8;
    const float rev[8] = {1.f, 1.f, 1.f, -1.f, 1.f, -1.f, -1.f, -1.f};
#pragma unroll
    for (int j = 0; j < 8; ++j)
      AtT[(size_t)(n * 8 + j) * 256 + m] = __float2bfloat16(ap[j] * rev[j]);
  } else if (b < 1024) {
    const int r = b - 512, m = t;
    yb[(size_t)r * 256 + m] = __float2bfloat16(y[((size_t)(r >> 3) * 256 + m) * 8 + (r & 7)]);
  } else {
    for (int i = t; i < 1056; i += 256)
      __hip_atomic_store(bar + i, 0, __ATOMIC_RELAXED, __HIP_MEMORY_SCOPE_AGENT);
  }
}

/* fused c + gram, 128x128 tiles (m93 shape). Blocks [0,128) compute cT
 * (4x32 tiles of yb x AtT^T); blocks [128,1152) compute GramT (32x32 tiles
 * of AtT x AtT^T). 256 thr = 4 waves (2x2), each wave a 64x64 sub-tile via
 * 4x4 MFMA16 fragments, K=256 direct from L2-resident sources. Pt pitch 130:
 * MFMA dump is 2-way banked (free), blade-recombine reads 4-way (same as the
 * old 64-tile kernel). Per-output accumulation order identical to the old
 * kernel -> bit-identical results. */
__global__ __launch_bounds__(256) void cg_kernel(const __hip_bfloat16* __restrict__ yb,
                                                 const __hip_bfloat16* __restrict__ AtT,
                                                 float* __restrict__ cT,
                                                 __hip_bfloat16* __restrict__ GrT) {
  __shared__ float Pt[128 * 130];  /* 66.6 KB */
  const int tid = threadIdx.x;
  const int wave = tid >> 6, lane = tid & 63;
  const int fr = lane & 15, fq = lane >> 4;
  const int wr = (wave >> 1) * 64, wc = (wave & 1) * 64;
  const int isC = blockIdx.x < 128;
  const int gb = isC ? blockIdx.x : blockIdx.x - 128;
  const int bx = gb & 31, by = gb >> 5;
  const int r0 = by * 128, c0 = bx * 128;
  const __hip_bfloat16* Asrc = isC ? yb : AtT;
  v4f acc[4][4] = {};
  for (int k0 = 0; k0 < 256; k0 += 32) {
    v8s a[4], b[4];
#pragma unroll
    for (int rr = 0; rr < 4; ++rr)
      a[rr] = *(const v8s*)(Asrc + (size_t)(r0 + wr + rr * 16 + fr) * 256 + k0 + fq * 8);
#pragma unroll
    for (int cc = 0; cc < 4; ++cc)
      b[cc] = *(const v8s*)(AtT + (size_t)(c0 + wc + cc * 16 + fr) * 256 + k0 + fq * 8);
#pragma unroll
    for (int rr = 0; rr < 4; ++rr)
#pragma unroll
      for (int cc = 0; cc < 4; ++cc)
        acc[rr][cc] = MFMA16(a[rr], b[cc], acc[rr][cc]);
  }
#pragma unroll
  for (int rr = 0; rr < 4; ++rr)
#pragma unroll
    for (int cc = 0; cc < 4; ++cc)
#pragma unroll
      for (int v = 0; v < 4; ++v)
        Pt[(wr + rr * 16 + fq * 4 + v) * 130 + wc + cc * 16 + fr] = acc[rr][cc][v];
  __syncthreads();
  if (isC) {
    /* 128 rows = 16 batches x 8 blades-i; 128 cols = 16 n x 8 blades-j */
    for (int o = tid; o < 2048; o += 256) {
      const int bl = o >> 7, k = (o >> 4) & 7, nl = o & 15;
      float s = 0.f;
#pragma unroll
      for (int j = 0; j < 8; ++j) {
        const int i = k ^ j;
        const float p = Pt[(bl * 8 + i) * 130 + nl * 8 + j];
        s += csign(i, j) ? -p : p;
      }
      cT[((size_t)((by * 16 + bl) * 8 + k)) * 512 + bx * 16 + nl] = s;
    }
  } else {
    /* rows: 16 n' x 8 i ; cols: 16 n x 8 j */
    const float rev[8] = {1.f, 1.f, 1.f, -1.f, 1.f, -1.f, -1.f, -1.f};
    for (int o = tid; o < 2048; o += 256) {
      const int nl = o >> 7, g = (o >> 4) & 7, npl = o & 15;
      float s = 0.f;
#pragma unroll
      for (int j = 0; j < 8; ++j) {
        const int i = g ^ j;
        const float sg = (csign(i, j) ? -1.f : 1.f) * rev[i];
        s += sg * Pt[(npl * 8 + i) * 130 + nl * 8 + j];
      }
      GrT[((size_t)((bx * 16 + nl) * 8 + g)) * 512 + by * 16 + npl] = __float2bfloat16(s);
    }
  }
}

/* Persistent kernel: 256 blocks x 512 thr, 1 block/CU.
 * Cluster = 16 blocks sharing bid&7 (same XCD under %8 mapping; verified at
 * runtime via HW_REG_XCC_ID purity check -> L2-poll protocol, else L3).
 * FROZEN: byte-identical to the R3/R7 build (193/192us, passed twice).
 * Evidence ledger: every variant touching the exchange (R2/R4/R8 structure,
 * R5/R6 store flavor) killed the container; R3/R7 passed. Do not touch. */
__global__ __launch_bounds__(512, 2) void ista_persist(
    const __hip_bfloat16* __restrict__ GrT, const float* __restrict__ cT,
    __hip_bfloat16* __restrict__ xb0, __hip_bfloat16* __restrict__ xb1,
    float* __restrict__ out, int* __restrict__ bars) {
  /* [0,32K) x-stage [32 rows][1024 B] (chunk c at slot c^(row&15)) |
   * [32K,+37376) Pt f32 [32][pitch 292] blade-swizzled */
  __shared__ __align__(16) char lds[32768 + 37376];
  float* const Pt = (float*)(lds + 32768);
  __shared__ int mode_sh;

  const int tid = threadIdx.x;
  const int wave = tid >> 6, lane = tid & 63;
  const int lr = lane & 31, lh = lane >> 5;  // tile row, k-half
  const int cl = (blockIdx.x & 7) * 2 + (blockIdx.x >> 7);
  const int w = (blockIdx.x >> 3) & 15;
  const int rowbase = cl * 32;
  int* const flags = bars + cl * 64;  /* 256B per cluster: no cross-cluster lines */
  int* const ctrl = bars + 1024;      /* [0]=arrive count, [1..8]=per-group XCD mask */

  /* persistent B in VGPRs: GramT rows [w*256 + wave*32 + lr], all K (plain
   * cached loads; GrT immutable and never invalidated - no fences anywhere) */
  v8s B[32];
  {
    const __hip_bfloat16* gB = GrT + (size_t)(w * 256 + wave * 32 + lr) * 512 + lh * 8;
#pragma unroll
    for (int kt = 0; kt < 32; ++kt) B[kt] = *(const v8s*)(gB + kt * 16);
  }

  /* one-time XCD purity probe + device barrier (overlaps the B loads above) */
  if (tid == 0) {
    unsigned xcc;
    asm volatile("s_getreg_b32 %0, hwreg(HW_REG_XCC_ID)" : "=s"(xcc));
    __hip_atomic_fetch_or((unsigned*)(ctrl + 1 + (blockIdx.x & 7)), 1u << (xcc & 31),
                          __ATOMIC_RELAXED, __HIP_MEMORY_SCOPE_AGENT);
    __hip_atomic_fetch_add(ctrl, 1, __ATOMIC_RELEASE, __HIP_MEMORY_SCOPE_AGENT);
    while (__hip_atomic_load(ctrl, __ATOMIC_RELAXED, __HIP_MEMORY_SCOPE_AGENT) < 256)
      __builtin_amdgcn_s_sleep(2);
    unsigned m = __hip_atomic_load((unsigned*)(ctrl + 1 + (blockIdx.x & 7)),
                                   __ATOMIC_RELAXED, __HIP_MEMORY_SCOPE_AGENT);
    mode_sh = (__popc(m) == 1) ? 1 : 0;
  }
  __syncthreads();
  const int fast = mode_sh;

  /* x-stage addressing */
  const int srow = tid >> 4, scol = tid & 15;
  /* epilogue mapping: 512 threads x 2 outputs (n = en*2 + {0,1}) */
  const int eb = tid >> 7, ek = (tid >> 4) & 7, en = tid & 15;
  const int xrow = rowbase + eb * 8 + ek;  // next-iter A row (b,i=k)
  const float thr = (ek == 0) ? 0.f : ((ek == 7) ? 0.002f : 0.001f);
  const float* const crow = cT + (size_t)(xrow)*512 + w * 32 + en * 2;
  const float cv0 = crow[0], cv1 = crow[1];  /* constant across iterations */
  float* const orow = out + ((size_t)(cl * 4 + eb) * 512 + w * 32 + en * 2) * 8 + ek;
  float xreg[2] = {0.f, 0.f};

  for (int it = 0; it < 50; ++it) {
    if (it > 0) {
      /* wait: all cluster members posted iter it (skip own slot) */
      if (tid < 16 && tid != w) {
        if (fast) {
          while (ld_flag_sc0(flags + tid) < it) __builtin_amdgcn_s_sleep(1);
        } else {
          while (__hip_atomic_load(flags + tid, __ATOMIC_RELAXED, __HIP_MEMORY_SCOPE_AGENT) < it)
            __builtin_amdgcn_s_sleep(1);
        }
      }
      asm volatile("" ::: "memory");
      __syncthreads();
      /* stage x_(it) into LDS: 32 rows x 1 KB */
      {
        const __hip_bfloat16* xr = (it & 1) ? xb1 : xb0;
        const __hip_bfloat16* g = xr + (size_t)(rowbase + srow) * 512 + scol * 8;
        v8s v0, v1, v2, v3;
        if (fast) {
          /* 4 pipelined sc0 loads (L1-bypass, L2-hit), one drain */
          asm volatile(
              "global_load_dwordx4 %0, %4, off sc0\n\t"
              "global_load_dwordx4 %1, %4, off offset:256 sc0\n\t"
              "global_load_dwordx4 %2, %4, off offset:512 sc0\n\t"
              "global_load_dwordx4 %3, %4, off offset:768 sc0\n\t"
              "s_waitcnt vmcnt(0)"
              : "=&v"(v0), "=&v"(v1), "=&v"(v2), "=&v"(v3)
              : "v"(g)
              : "memory");
        } else {
          v0 = aload16(g);
          v1 = aload16(g + 128);
          v2 = aload16(g + 256);
          v3 = aload16(g + 384);
        }
        const int sw = srow & 15;
        *(v8s*)(lds + srow * 1024 + (((scol + 0) ^ sw) << 4)) = v0;
        *(v8s*)(lds + srow * 1024 + (((scol + 16) ^ sw) << 4)) = v1;
        *(v8s*)(lds + srow * 1024 + (((scol + 32) ^ sw) << 4)) = v2;
        *(v8s*)(lds + srow * 1024 + (((scol + 48) ^ sw) << 4)) = v3;
      }
      __syncthreads();
      /* K-loop: 32 MFMAs in two independent chains, B from regs, A from LDS
       * (2-way swizzle = free). Dual chains halve dependent-chain latency. */
      v16f acc0 = {}, acc1 = {};
#pragma unroll
      for (int kt = 0; kt < 32; kt += 2) {
        v8s a0 = *(const v8s*)(lds + lr * 1024 + (((kt * 2 + lh) ^ (lr & 15)) << 4));
        v8s a1 = *(const v8s*)(lds + lr * 1024 + ((((kt + 1) * 2 + lh) ^ (lr & 15)) << 4));
        acc0 = MFMA32(a0, B[kt], acc0);
        acc1 = MFMA32(a1, B[kt + 1], acc1);
      }
      /* dump P tile: C/D layout col=lane&31, row=(r&3)+8*(r>>2)+4*(lane>>5).
       * col=(n,g): store g at slot g^(row&7) inside the 9-float n-slot. */
      {
        const int nsl = ((wave * 32 + lr) >> 3) * 9;
        const int gg = lr & 7;
#pragma unroll
        for (int r = 0; r < 16; ++r) {
          const int row = (r & 3) + 8 * (r >> 2) + 4 * lh;
          Pt[row * 292 + nsl + (gg ^ (row & 7))] = acc0[r] + acc1[r];
        }
      }
    }
    __syncthreads(); /* Pt visible */
    /* epilogue: blade recombine + ISTA update + x publish */
    {
      __hip_bfloat16* const xw = (it & 1) ? xb0 : xb1;
      unsigned int pack = 0;
#pragma unroll
      for (int c = 0; c < 2; ++c) {
        const int n = en * 2 + c;
        float s = 0.f;
        if (it > 0) {
          /* slot index = j ^ i = ek (constant per thread) -> 2-way banks */
          const float* pb = Pt + (size_t)(eb * 8) * 292 + n * 9 + ek;
#pragma unroll
          for (int j = 0; j < 8; ++j) {
            const int i = ek ^ j;
            const float p = pb[i * 292];
            s += csign(i, j) ? -p : p;
          }
        }
        float xv = xreg[c] - STEPSZ * (s - (c ? cv1 : cv0));
        const float ax = fabsf(xv) - thr;
        xv = (ax > 0.f) ? copysignf(ax, xv) : 0.f;
        xreg[c] = xv;
        __hip_bfloat16 h = __float2bfloat16(xv);
        unsigned short bits;
        __builtin_memcpy(&bits, &h, 2);
        pack |= ((unsigned int)bits) << (c * 16);
        if (it == 49) orow[c * 8] = xv;
      }
      unsigned int* const pdst =
          (unsigned int*)(xw + (size_t)xrow * 512 + w * 32 + en * 2);
      if (fast) {
        *(volatile unsigned int*)pdst = pack; /* write-through -> shared L2 */
      } else {
        __hip_atomic_store(pdst, pack, __ATOMIC_RELAXED, __HIP_MEMORY_SCOPE_AGENT);
      }
    }
    __syncthreads(); /* per-wave vmcnt(0) drain -> all stores at L2/L3 */
    if (tid == 0) {
      if (fast)
        *(volatile int*)(flags + w) = it + 1;
      else
        __hip_atomic_store(flags + w, it + 1, __ATOMIC_RELAXED, __HIP_MEMORY_SCOPE_AGENT);
    }
  }
}

extern "C" void kernel_launch(void* const* d_in, const int* in_sizes, int n_in,
                              void* d_out, int out_size, void* d_ws, size_t ws_size,
                              hipStream_t stream) {
  (void)in_sizes; (void)n_in; (void)out_size; (void)ws_size;
  const float* y = (const float*)d_in[0];
  const float* A = (const float*)d_in[1];
  float* out = (float*)d_out;
  char* ws = (char*)d_ws;

  __hip_bfloat16* AtT = (__hip_bfloat16*)(ws + OFF_ATT);
  __hip_bfloat16* GrT = (__hip_bfloat16*)(ws + OFF_GRT);
  float* cT = (float*)(ws + OFF_CT);
  __hip_bfloat16* yb = (__hip_bfloat16*)(ws + OFF_YB);
  __hip_bfloat16* xb0 = (__hip_bfloat16*)(ws + OFF_XB0);
  __hip_bfloat16* xb1 = (__hip_bfloat16*)(ws + OFF_XB1);
  int* bars = (int*)(ws + OFF_BAR);

  prep_fused<<<1025, 256, 0, stream>>>(A, y, AtT, yb, bars);
  cg_kernel<<<1152, 256, 0, stream>>>(yb, AtT, cT, GrT);
  ista_persist<<<256, 512, 0, stream>>>(GrT, cT, xb0, xb1, out, bars);
}